// Round 1
// baseline (819.187 us; speedup 1.0000x reference)
//
#include <hip/hip_runtime.h>
#include <stdint.h>

// LSTM decoder: VOCAB=32000, EMBED=512, HIDDEN=1024, B=32, S=48.
// Plan:
//   1. cast W_ih, W_hh, fc_W, hidden -> bf16 (ws)
//   2. gather X[s][b][:] = emb[inputs[b][s]] as bf16
//   3. GEMM1: Xg[1536,4096] = X @ W_ih^T + b_ih + b_hh   (fp32 out)
//   4. 48x lstm_step: gates = Xg[t] + h @ W_hh^T; activations; h->H_all[t+1]
//   5. GEMM2: out[b][s][v] = H_all[1..48] @ fc_W^T + fc_b (fp32 out, scatter)

typedef unsigned short u16;
typedef __attribute__((ext_vector_type(8))) short bf16x8;
typedef __attribute__((ext_vector_type(4))) float floatx4;
struct alignas(8) us4 { u16 x, y, z, w; };

#define BATCH 32
#define SEQ   48
#define EMBED 512
#define HID   1024
#define VOCAB 32000
#define MROWS (SEQ * BATCH)   // 1536

__device__ __forceinline__ u16 f2bf(float f) {
  unsigned u = __float_as_uint(f);
  u += 0x7FFF + ((u >> 16) & 1);   // round-to-nearest-even
  return (u16)(u >> 16);
}

__device__ __forceinline__ floatx4 mfma16(bf16x8 a, bf16x8 b, floatx4 c) {
  return __builtin_amdgcn_mfma_f32_16x16x32_bf16(a, b, c, 0, 0, 0);
}

// async global->LDS, 16B per lane; lds base must be wave-uniform
typedef __attribute__((address_space(1))) unsigned int as1_uint;
typedef __attribute__((address_space(3))) unsigned int as3_uint;
__device__ __forceinline__ void gl_lds16(const void* g, void* l) {
  __builtin_amdgcn_global_load_lds((as1_uint*)g, (as3_uint*)l, 16, 0, 0);
}

__device__ __forceinline__ float sigmoidf_(float x) {
  return 1.0f / (1.0f + __expf(-x));
}

// ---------------- cast fp32 -> bf16, 4 elems/thread, n % 4 == 0 ----------------
__global__ void cast_kernel(const float* __restrict__ in, u16* __restrict__ out, int n4) {
  int i = blockIdx.x * blockDim.x + threadIdx.x;
  if (i < n4) {
    float4 v = *(const float4*)(in + (size_t)i * 4);
    us4 o;
    o.x = f2bf(v.x); o.y = f2bf(v.y); o.z = f2bf(v.z); o.w = f2bf(v.w);
    *(us4*)(out + (size_t)i * 4) = o;
  }
}

// ---------------- embedding gather: X[s*32+b][:] = bf16(emb[idx[b][s]]) --------
__global__ void gather_kernel(const int* __restrict__ idx, const float* __restrict__ emb,
                              u16* __restrict__ X) {
  int bid = blockIdx.x;          // = s*32 + b
  int s = bid >> 5, b = bid & 31;
  int t = idx[b * SEQ + s];
  const float* src = emb + (size_t)t * EMBED;
  u16* dst = X + (size_t)bid * EMBED;
  int e = threadIdx.x * 4;       // 128 threads * 4 = 512
  float4 v = *(const float4*)(src + e);
  us4 o;
  o.x = f2bf(v.x); o.y = f2bf(v.y); o.z = f2bf(v.z); o.w = f2bf(v.w);
  *(us4*)(dst + e) = o;
}

// ---------------- tiled bf16 GEMM: C = A[M,K] @ B[N,K]^T + bias ----------------
// 128x128 tile, BK=64, 4 waves, each wave 64x64 via 4x4 16x16x32 MFMA tiles.
// LDS chunks (16B) XOR-swizzled by row to avoid ds_read_b128 bank conflicts;
// swizzle is applied to the per-lane GLOBAL address so global_load_lds's
// wave-uniform-base + lane*16 LDS destination stays contiguous.
// out_mode 0: C[m*N + n]   (row-major)
// out_mode 1: C[(b*SEQ + s)*N + n] with b=m&31, s=m>>5  (logits scatter)
__global__ __launch_bounds__(256) void gemm_bt_kernel(
    const u16* __restrict__ A, const u16* __restrict__ B,
    const float* __restrict__ bias0, const float* __restrict__ bias1,
    float* __restrict__ C, int M, int N, int K, int out_mode) {
  __shared__ u16 As[128 * 64];   // row r: 8 chunks of 8 bf16; chunk p holds global chunk p^(r&7)
  __shared__ u16 Bs[128 * 64];

  const int tid = threadIdx.x;
  const int wave = tid >> 6, lane = tid & 63;
  const int l3 = lane >> 3, l7 = lane & 7;
  const int q = lane >> 4, rf = lane & 15;
  const int tn = blockIdx.x, tm = blockIdx.y;
  const int gm0 = tm * 128, gn0 = tn * 128;
  const int wm = (wave & 1) * 64, wn = (wave >> 1) * 64;

  floatx4 acc[4][4];
#pragma unroll
  for (int i = 0; i < 4; ++i)
#pragma unroll
    for (int j = 0; j < 4; ++j) acc[i][j] = (floatx4){0.f, 0.f, 0.f, 0.f};

  for (int k0 = 0; k0 < K; k0 += 64) {
    // stage: 16 wave-issues each cover 8 rows x 8 chunks (1 KiB LDS)
#pragma unroll
    for (int i = 0; i < 4; ++i) {
      int e = wave * 4 + i;
      int r = e * 8 + l3;
      int qd = l7 ^ (r & 7);
      gl_lds16(A + (size_t)(gm0 + r) * K + k0 + qd * 8, (void*)(As + e * 512));
      gl_lds16(B + (size_t)(gn0 + r) * K + k0 + qd * 8, (void*)(Bs + e * 512));
    }
    __syncthreads();   // compiler emits vmcnt(0) drain before barrier

#pragma unroll
    for (int kk = 0; kk < 64; kk += 32) {
      int jc = (kk >> 3) + q;   // global 16B chunk index for this quad
      bf16x8 af[4], bf[4];
#pragma unroll
      for (int mi = 0; mi < 4; ++mi) {
        int r = wm + mi * 16 + rf;
        af[mi] = *(const bf16x8*)(As + r * 64 + (jc ^ (r & 7)) * 8);
      }
#pragma unroll
      for (int ni = 0; ni < 4; ++ni) {
        int r = wn + ni * 16 + rf;
        bf[ni] = *(const bf16x8*)(Bs + r * 64 + (jc ^ (r & 7)) * 8);
      }
#pragma unroll
      for (int mi = 0; mi < 4; ++mi)
#pragma unroll
        for (int ni = 0; ni < 4; ++ni)
          acc[mi][ni] = mfma16(af[mi], bf[ni], acc[mi][ni]);
    }
    __syncthreads();
  }

  // epilogue: D row = q*4 + reg (m), col = lane&15 (n)
#pragma unroll
  for (int ni = 0; ni < 4; ++ni) {
    int n = gn0 + wn + ni * 16 + rf;
    float bv = bias0[n];
    if (bias1) bv += bias1[n];
#pragma unroll
    for (int mi = 0; mi < 4; ++mi) {
#pragma unroll
      for (int r = 0; r < 4; ++r) {
        int m = gm0 + wm + mi * 16 + q * 4 + r;
        float val = acc[mi][ni][r] + bv;
        if (out_mode == 0) {
          C[(size_t)m * N + n] = val;
        } else {
          int b = m & 31, s = m >> 5;
          C[((size_t)b * SEQ + s) * N + n] = val;
        }
      }
    }
  }
}

// ---------------- one LSTM time step (fused small-GEMM + activations) ----------
// 256 WGs x 256 thr. WG g owns 4 hidden units u0=g*4; its b-frag packs the 16
// W_hh rows {i,f,g,o} x {u0..u0+3}. 4 waves split K (256 each), LDS-reduce.
__global__ __launch_bounds__(256) void lstm_step_kernel(
    const u16* __restrict__ h_prev,   // [32][1024] bf16
    const u16* __restrict__ Whh,      // [4096][1024] bf16
    const float* __restrict__ xg,     // [32][4096] fp32 (input gates + biases)
    const float* __restrict__ c_in,   // [32][1024] fp32
    float* __restrict__ c_out,        // [32][1024] fp32
    u16* __restrict__ h_out) {        // [32][1024] bf16
  const int u0 = blockIdx.x * 4;
  const int tid = threadIdx.x;
  const int wave = tid >> 6, lane = tid & 63;
  const int q = lane >> 4, rf = lane & 15;
  const int gate = rf >> 2, du = rf & 3;
  const int brow = gate * HID + u0 + du;      // W_hh row for this lane's n-index

  floatx4 acc0 = {0.f, 0.f, 0.f, 0.f}, acc1 = {0.f, 0.f, 0.f, 0.f};
  const u16* wp = Whh + (size_t)brow * HID + wave * 256 + q * 8;
  const u16* a0p = h_prev + (size_t)rf * HID + wave * 256 + q * 8;
  const u16* a1p = a0p + 16 * HID;
#pragma unroll
  for (int ks = 0; ks < 256; ks += 32) {
    bf16x8 bv = *(const bf16x8*)(wp + ks);
    bf16x8 a0 = *(const bf16x8*)(a0p + ks);
    bf16x8 a1 = *(const bf16x8*)(a1p + ks);
    acc0 = mfma16(a0, bv, acc0);
    acc1 = mfma16(a1, bv, acc1);
  }

  __shared__ float red[4][32][16];   // [wave][batch][n]
#pragma unroll
  for (int r = 0; r < 4; ++r) {
    red[wave][q * 4 + r][rf] = acc0[r];
    red[wave][16 + q * 4 + r][rf] = acc1[r];
  }
  __syncthreads();

  if (tid < 128) {
    int b = tid >> 2, d = tid & 3;
    int u = u0 + d;
    float g4[4];
#pragma unroll
    for (int gt = 0; gt < 4; ++gt) {
      int n = gt * 4 + d;
      float v = red[0][b][n] + red[1][b][n] + red[2][b][n] + red[3][b][n];
      v += xg[b * 4096 + gt * HID + u];
      g4[gt] = v;
    }
    float i_ = sigmoidf_(g4[0]);
    float f_ = sigmoidf_(g4[1]);
    float gg = tanhf(g4[2]);
    float o_ = sigmoidf_(g4[3]);
    float c = f_ * c_in[b * HID + u] + i_ * gg;
    float h = o_ * tanhf(c);
    c_out[b * HID + u] = c;
    h_out[b * HID + u] = f2bf(h);
  }
}

extern "C" void kernel_launch(void* const* d_in, const int* in_sizes, int n_in,
                              void* d_out, int out_size, void* d_ws, size_t ws_size,
                              hipStream_t stream) {
  const int*   inputs = (const int*)d_in[0];
  const float* hidden = (const float*)d_in[1];
  const float* cell   = (const float*)d_in[2];
  const float* emb    = (const float*)d_in[3];
  const float* W_ih   = (const float*)d_in[4];
  const float* W_hh   = (const float*)d_in[5];
  const float* b_ih   = (const float*)d_in[6];
  const float* b_hh   = (const float*)d_in[7];
  const float* fc_W   = (const float*)d_in[8];
  const float* fc_b   = (const float*)d_in[9];
  float* out = (float*)d_out;

  char* ws = (char*)d_ws;
  // workspace layout (all 256B aligned), total ~103 MiB
  u16*   Xbf  = (u16*)(ws);                                  // 1536*512   bf16 = 1,572,864 B
  u16*   Wihb = (u16*)(ws + 1572864);                        // 4096*512   bf16 = 4,194,304 B
  u16*   Whhb = (u16*)(ws + 1572864 + 4194304);              // 4096*1024  bf16 = 8,388,608 B
  u16*   fcWb = (u16*)(ws + 14155776);                       // 32000*1024 bf16 = 65,536,000 B
  float* Xg   = (float*)(ws + 14155776 + 65536000);          // 1536*4096  f32  = 25,165,824 B
  u16*   Hall = (u16*)(ws + 104857600);                      // 49*32*1024 bf16 = 3,211,264 B
  float* c_ws = (float*)(ws + 104857600 + 3211264);          // 32*1024    f32  = 131,072 B

  // 1) casts to bf16
  cast_kernel<<<(4096 * 512 / 4 + 255) / 256, 256, 0, stream>>>(W_ih, Wihb, 4096 * 512 / 4);
  cast_kernel<<<(4096 * 1024 / 4 + 255) / 256, 256, 0, stream>>>(W_hh, Whhb, 4096 * 1024 / 4);
  cast_kernel<<<(VOCAB * 1024 / 4 + 255) / 256, 256, 0, stream>>>(fc_W, fcWb, VOCAB * 1024 / 4);
  cast_kernel<<<(BATCH * HID / 4 + 255) / 256, 256, 0, stream>>>(hidden, Hall, BATCH * HID / 4); // h0 -> slot 0

  // 2) embedding gather (time-major)
  gather_kernel<<<MROWS, 128, 0, stream>>>(inputs, emb, Xbf);

  // 3) GEMM1: Xg = X @ W_ih^T + b_ih + b_hh
  gemm_bt_kernel<<<dim3(4096 / 128, MROWS / 128), 256, 0, stream>>>(
      Xbf, Wihb, b_ih, b_hh, Xg, MROWS, 4096, EMBED, 0);

  // 4) 48 recurrent steps
  for (int s = 0; s < SEQ; ++s) {
    lstm_step_kernel<<<256, 256, 0, stream>>>(
        Hall + (size_t)s * BATCH * HID, Whhb, Xg + (size_t)s * BATCH * 4096,
        (s == 0) ? cell : c_ws, c_ws, Hall + (size_t)(s + 1) * BATCH * HID);
  }

  // 5) GEMM2: logits = H_all[1..48] @ fc_W^T + fc_b, scattered to [B][S][V]
  gemm_bt_kernel<<<dim3(VOCAB / 128, MROWS / 128), 256, 0, stream>>>(
      Hall + (size_t)BATCH * HID, fcWb, fc_b, (const float*)nullptr, out,
      MROWS, VOCAB, HID, 1);
}